// Round 6
// baseline (4316.653 us; speedup 1.0000x reference)
//
#include <hip/hip_runtime.h>
#include <math.h>

#define BB 2
#define SS 1024
#define DD 1024
#define HH 16
#define LL 8
#define FFS 2752            // source F
#define FFP 2816            // padded F (divisible by 128)
#define VV 32000
#define DKH 64
#define MM (BB*SS)          // 2048 rows
#define QKVLD 3072          // fused qkv row stride
#define UPLD  5632          // fused w1|w3 output row stride
#define HCHUNK 3200         // head gemm N-chunk (25 tiles of 128, 10 chunks)

typedef unsigned short u16;
typedef unsigned int   u32;
typedef __attribute__((ext_vector_type(4))) float  f32x4;
typedef __attribute__((ext_vector_type(8))) __bf16 bf16x8;

__device__ inline u16 f2bf(float f) {
    u32 u = __float_as_uint(f);
    u += 0x7FFFu + ((u >> 16) & 1u);   // RNE
    return (u16)(u >> 16);
}

// ---------------- RoPE tables ----------------
__global__ void k_rope_tables(float* __restrict__ st, float* __restrict__ ct) {
    int idx = blockIdx.x * 256 + threadIdx.x;
    if (idx >= SS * (DKH / 2)) return;
    int s = idx >> 5;
    int i = idx & 31;
    float inv = powf(10000.0f, -((float)(2 * i)) / (float)DKH);
    float f = (float)s * inv;
    st[idx] = sinf(f);
    ct[idx] = cosf(f);
}

// ---------------- Embedding gather (fp32 residual) ----------------
__global__ __launch_bounds__(256) void k_embed(const int* __restrict__ ids,
                                               const float* __restrict__ emb,
                                               float* __restrict__ x) {
    int row = blockIdx.x;
    int id = ids[row];
    const float4* src = (const float4*)(emb + (size_t)id * DD);
    float4* dst = (float4*)(x + (size_t)row * DD);
    dst[threadIdx.x] = src[threadIdx.x];
}

// ---------------- RMSNorm fp32 -> bf16 ----------------
__global__ __launch_bounds__(256) void k_rmsnorm_bf16(const float* __restrict__ x,
                                                      const float* __restrict__ g,
                                                      u16* __restrict__ o) {
    int row = blockIdx.x;
    int t = threadIdx.x;
    float4 v = ((const float4*)(x + (size_t)row * DD))[t];
    float ss = v.x * v.x + v.y * v.y + v.z * v.z + v.w * v.w;
#pragma unroll
    for (int off = 32; off > 0; off >>= 1) ss += __shfl_xor(ss, off, 64);
    __shared__ float wsum[4];
    if ((t & 63) == 0) wsum[t >> 6] = ss;
    __syncthreads();
    float tot = wsum[0] + wsum[1] + wsum[2] + wsum[3];
    float rms = sqrtf(tot * (1.0f / DD) + 1e-5f);
    float4 gv = ((const float4*)g)[t];
    ushort4 r;
    r.x = f2bf(v.x / rms * gv.x);
    r.y = f2bf(v.y / rms * gv.y);
    r.z = f2bf(v.z / rms * gv.z);
    r.w = f2bf(v.w / rms * gv.w);
    *(ushort4*)(o + (size_t)row * DD + t * 4) = r;
}

// ---------------- Weight cast fp32 -> bf16 (optional row/col zero-pad) ----------------
__global__ __launch_bounds__(256) void k_castw(const float* __restrict__ src,
                                               u16* __restrict__ dst,
                                               int src_rows, int src_c4, int dst_c4) {
    int r = blockIdx.y;
    int c4 = blockIdx.x * 256 + threadIdx.x;
    if (c4 >= dst_c4) return;
    float4 v = make_float4(0.f, 0.f, 0.f, 0.f);
    if (r < src_rows && c4 < src_c4)
        v = *(const float4*)(src + (size_t)r * (src_c4 * 4) + c4 * 4);
    ushort4 o;
    o.x = f2bf(v.x); o.y = f2bf(v.y); o.z = f2bf(v.z); o.w = f2bf(v.w);
    *(ushort4*)(dst + (size_t)r * (dst_c4 * 4) + c4 * 4) = o;
}

// ---------------- bf16 MFMA GEMM ----------------
// Y[m][n] (+R) = sum_k X[m][k]*W[n][k].  X:[2048][K] bf16, W:[N][K] bf16 (N = grid.x*128)
// tile 128x128, BK=32, 4 waves (2x2), 4x4 16x16x32 fragments per wave.
// LDS layout [kb 0..3][m 0..127] in 16B granules:
//   frag ds_read_b128: 16 lanes x contiguous 16B -> conflict-free
//   staging ds_write_b128: adjacent lanes 4096B apart -> 2-way alias (free, m136)
__global__ __launch_bounds__(256) void k_gemm_bf16(const u16* __restrict__ X,
                                                   const u16* __restrict__ W,
                                                   const float* __restrict__ R,
                                                   float* __restrict__ Y,
                                                   int K, int ldy) {
    __shared__ uint4 As[512];
    __shared__ uint4 Bs[512];
    const int t = threadIdx.x;
    const int l = t & 63;
    const int w = t >> 6;
    const int wr = w >> 1, wc = w & 1;
    const int m0 = blockIdx.y * 128, n0 = blockIdx.x * 128;

    // staging: thread t covers tile-row sm = t>>1, k-granules {skb, skb+1}, skb=(t&1)*2
    const int sm  = t >> 1;
    const int skb = (t & 1) * 2;
    const u16* Xp = X + (size_t)(m0 + sm) * K + skb * 8;
    const u16* Wp = W + (size_t)(n0 + sm) * K + skb * 8;
    const int sl0 = skb * 128 + sm, sl1 = (skb + 1) * 128 + sm;

    // fragment bases: lane l -> k-granule l>>4, row/col l&15
    const int kb  = l >> 4;
    const int fra = kb * 128 + wr * 64 + (l & 15);
    const int frb = kb * 128 + wc * 64 + (l & 15);

    f32x4 acc[4][4];
    f32x4 z4 = {0.f, 0.f, 0.f, 0.f};
#pragma unroll
    for (int i = 0; i < 4; ++i)
#pragma unroll
        for (int j = 0; j < 4; ++j) acc[i][j] = z4;

    uint4 ax0 = *(const uint4*)(Xp);
    uint4 ax1 = *(const uint4*)(Xp + 8);
    uint4 bx0 = *(const uint4*)(Wp);
    uint4 bx1 = *(const uint4*)(Wp + 8);

    for (int k0 = 0; k0 < K; k0 += 32) {
        __syncthreads();                 // previous iteration's frag reads done
        As[sl0] = ax0; As[sl1] = ax1;
        Bs[sl0] = bx0; Bs[sl1] = bx1;
        __syncthreads();
        if (k0 + 32 < K) {               // uniform prefetch branch
            ax0 = *(const uint4*)(Xp + k0 + 32);
            ax1 = *(const uint4*)(Xp + k0 + 40);
            bx0 = *(const uint4*)(Wp + k0 + 32);
            bx1 = *(const uint4*)(Wp + k0 + 40);
        }
        bf16x8 af[4], bfr[4];
#pragma unroll
        for (int mi = 0; mi < 4; ++mi)
            af[mi] = __builtin_bit_cast(bf16x8, As[fra + mi * 16]);
#pragma unroll
        for (int ni = 0; ni < 4; ++ni)
            bfr[ni] = __builtin_bit_cast(bf16x8, Bs[frb + ni * 16]);
#pragma unroll
        for (int mi = 0; mi < 4; ++mi)
#pragma unroll
            for (int ni = 0; ni < 4; ++ni)
                acc[mi][ni] = __builtin_amdgcn_mfma_f32_16x16x32_bf16(
                    af[mi], bfr[ni], acc[mi][ni], 0, 0, 0);
    }

    // C/D layout (m89/m91-verified): col = lane&15, row = (lane>>4)*4 + reg
    const int r0 = m0 + wr * 64 + (l >> 4) * 4;
    const int c0 = n0 + wc * 64 + (l & 15);
#pragma unroll
    for (int mi = 0; mi < 4; ++mi)
#pragma unroll
        for (int j = 0; j < 4; ++j) {
            size_t rowoff = (size_t)(r0 + mi * 16 + j) * ldy + c0;
#pragma unroll
            for (int ni = 0; ni < 4; ++ni) {
                float v = acc[mi][ni][j];
                if (R) v += R[rowoff + ni * 16];
                Y[rowoff + ni * 16] = v;
            }
        }
}

// ---------------- RoPE (in-place on fused qkv; q: cols 0..1023, k: 1024..2047) ----------------
__global__ __launch_bounds__(256) void k_rope(float* __restrict__ qkv,
                                              const float* __restrict__ st,
                                              const float* __restrict__ ct) {
    int seg = blockIdx.y * 1024;
    int idx = blockIdx.x * 256 + threadIdx.x;
    int row = idx >> 9;
    int p = idx & 511;
    int i = p & 31;                      // pair index within 64-dim head
    int s = row & (SS - 1);
    float sv = st[s * 32 + i], cv = ct[s * 32 + i];
    size_t base = (size_t)row * QKVLD + seg + 2 * p;
    float2 xv = *(float2*)(qkv + base);
    float2 r;
    r.x = xv.x * cv - xv.y * sv;
    r.y = xv.x * sv + xv.y * cv;
    *(float2*)(qkv + base) = r;
}

// ---------------- SiLU(f1) * f3 -> bf16 ----------------
__global__ __launch_bounds__(256) void k_silu_mul(const float* __restrict__ f13,
                                                  u16* __restrict__ f1b) {
    int r = blockIdx.y;
    int c4 = blockIdx.x * 256 + threadIdx.x;
    if (c4 >= FFP / 4) return;
    float4 a = *(const float4*)(f13 + (size_t)r * UPLD + c4 * 4);
    float4 b = *(const float4*)(f13 + (size_t)r * UPLD + FFP + c4 * 4);
    ushort4 o;
    o.x = f2bf(a.x / (1.f + expf(-a.x)) * b.x);
    o.y = f2bf(a.y / (1.f + expf(-a.y)) * b.y);
    o.z = f2bf(a.z / (1.f + expf(-a.z)) * b.z);
    o.w = f2bf(a.w / (1.f + expf(-a.w)) * b.w);
    *(ushort4*)(f1b + (size_t)r * FFP + c4 * 4) = o;
}

// ---------------- Flash-style causal attention (fp32 compute, bf16 out) ----------------
__global__ __launch_bounds__(256) void k_attn(const float* __restrict__ QKV,
                                              u16* __restrict__ O) {
    __shared__ float Qs[64][65];
    __shared__ float Ks[64][65];
    __shared__ float Vs[64][65];
    __shared__ float Ps[64][65];
    const int qt = blockIdx.x, hh = blockIdx.y, b = blockIdx.z;
    const int t = threadIdx.x;
    const int tx = t & 15, ty = t >> 4;
    const float* Qb = QKV + (size_t)b * SS * QKVLD + (size_t)hh * DKH;
    const float* Kb = Qb + 1024;
    const float* Vb = Qb + 2048;

#pragma unroll
    for (int it = 0; it < 4; ++it) {
        int idx = t + it * 256;
        int r = idx >> 4, c = (idx & 15) << 2;
        float4 a = *(const float4*)(Qb + (size_t)(qt * 64 + r) * QKVLD + c);
        Qs[r][c] = a.x; Qs[r][c + 1] = a.y; Qs[r][c + 2] = a.z; Qs[r][c + 3] = a.w;
    }
    float m[4], l[4], o[4][4];
#pragma unroll
    for (int i = 0; i < 4; ++i) {
        m[i] = -INFINITY; l[i] = 0.f;
#pragma unroll
        for (int j = 0; j < 4; ++j) o[i][j] = 0.f;
    }
    for (int kt = 0; kt <= qt; ++kt) {
        __syncthreads();   // Q staged (iter 0) / prev PV reads done (later)
#pragma unroll
        for (int it = 0; it < 4; ++it) {
            int idx = t + it * 256;
            int r = idx >> 4, c = (idx & 15) << 2;
            float4 a = *(const float4*)(Kb + (size_t)(kt * 64 + r) * QKVLD + c);
            Ks[r][c] = a.x; Ks[r][c + 1] = a.y; Ks[r][c + 2] = a.z; Ks[r][c + 3] = a.w;
            float4 vv = *(const float4*)(Vb + (size_t)(kt * 64 + r) * QKVLD + c);
            Vs[r][c] = vv.x; Vs[r][c + 1] = vv.y; Vs[r][c + 2] = vv.z; Vs[r][c + 3] = vv.w;
        }
        __syncthreads();
        float sc[4][4] = {{0.f}};
#pragma unroll
        for (int kk = 0; kk < 64; ++kk) {
            float qv[4], kv[4];
#pragma unroll
            for (int i = 0; i < 4; ++i) qv[i] = Qs[ty * 4 + i][kk];
#pragma unroll
            for (int j = 0; j < 4; ++j) kv[j] = Ks[tx * 4 + j][kk];
#pragma unroll
            for (int i = 0; i < 4; ++i)
#pragma unroll
                for (int j = 0; j < 4; ++j)
                    sc[i][j] = fmaf(qv[i], kv[j], sc[i][j]);
        }
        const bool diag = (kt == qt);
#pragma unroll
        for (int i = 0; i < 4; ++i)
#pragma unroll
            for (int j = 0; j < 4; ++j) {
                float s = sc[i][j] * 0.125f;
                if (diag && (tx * 4 + j > ty * 4 + i)) s = -INFINITY;
                sc[i][j] = s;
            }
#pragma unroll
        for (int i = 0; i < 4; ++i) {
            float rmax = fmaxf(fmaxf(sc[i][0], sc[i][1]), fmaxf(sc[i][2], sc[i][3]));
#pragma unroll
            for (int off = 8; off > 0; off >>= 1)
                rmax = fmaxf(rmax, __shfl_xor(rmax, off, 16));
            float mn = fmaxf(m[i], rmax);
            float corr = expf(m[i] - mn);
            m[i] = mn;
            float rs = 0.f;
#pragma unroll
            for (int j = 0; j < 4; ++j) {
                float p = expf(sc[i][j] - mn);
                Ps[ty * 4 + i][tx * 4 + j] = p;
                rs += p;
            }
#pragma unroll
            for (int off = 8; off > 0; off >>= 1)
                rs += __shfl_xor(rs, off, 16);
            l[i] = l[i] * corr + rs;
#pragma unroll
            for (int j = 0; j < 4; ++j) o[i][j] *= corr;
        }
        __syncthreads();   // Ps complete before PV
#pragma unroll
        for (int kk = 0; kk < 64; ++kk) {
            float pv[4], vv[4];
#pragma unroll
            for (int i = 0; i < 4; ++i) pv[i] = Ps[ty * 4 + i][kk];
#pragma unroll
            for (int j = 0; j < 4; ++j) vv[j] = Vs[kk][tx * 4 + j];
#pragma unroll
            for (int i = 0; i < 4; ++i)
#pragma unroll
                for (int j = 0; j < 4; ++j)
                    o[i][j] = fmaf(pv[i], vv[j], o[i][j]);
        }
    }
    u16* Ob = O + (size_t)b * SS * DD + (size_t)hh * DKH;
#pragma unroll
    for (int i = 0; i < 4; ++i) {
        float inv = 1.0f / l[i];
        int r = qt * 64 + ty * 4 + i;
        ushort4 y;
        y.x = f2bf(o[i][0] * inv); y.y = f2bf(o[i][1] * inv);
        y.z = f2bf(o[i][2] * inv); y.w = f2bf(o[i][3] * inv);
        *(ushort4*)(Ob + (size_t)r * DD + tx * 4) = y;
    }
}

extern "C" void kernel_launch(void* const* d_in, const int* in_sizes, int n_in,
                              void* d_out, int out_size, void* d_ws, size_t ws_size,
                              hipStream_t stream) {
    const int*   ids = (const int*)d_in[0];
    const float* emb = (const float*)d_in[1];
    const float* Wq  = (const float*)d_in[2];
    const float* Wk  = (const float*)d_in[3];
    const float* Wv  = (const float*)d_in[4];
    const float* Wo  = (const float*)d_in[5];
    const float* W1  = (const float*)d_in[6];
    const float* W2  = (const float*)d_in[7];
    const float* W3  = (const float*)d_in[8];
    const float* g1  = (const float*)d_in[9];
    const float* g2  = (const float*)d_in[10];
    const float* gf  = (const float*)d_in[11];
    const float* Wh  = (const float*)d_in[12];
    float* out = (float*)d_out;

    // ---- ws (~19 MB): residual x, bf16 activations hb, head-chunk weights, rope tables
    float* x   = (float*)d_ws;                       // [2048][1024] f32
    u16*   hb  = (u16*)(x + (size_t)MM * DD);        // [2048][1024] bf16
    u16*   whb = hb + (size_t)MM * DD;               // [3200][1024] bf16
    float* st  = (float*)(whb + (size_t)HCHUNK * DD);
    float* ct  = st + SS * 32;

    // ---- d_out scratch (~26.6M of 65.5M floats; all dead before head GEMM)
    float* qkv  = out;                                // [2048][3072] f32
    float* f13  = qkv + (size_t)MM * QKVLD;           // [2048][5632] f32
    u16*   wqkv = (u16*)(f13 + (size_t)MM * UPLD);    // [3072][1024] bf16
    u16*   w13b = wqkv + (size_t)3072 * DD;           // [5632][1024] bf16
    u16*   w2b  = w13b + (size_t)UPLD * DD;           // [1024][2816] bf16
    u16*   f1b  = w2b + (size_t)DD * FFP;             // [2048][2816] bf16

    k_rope_tables<<<(SS * 32 + 255) / 256, 256, 0, stream>>>(st, ct);
    k_embed<<<MM, 256, 0, stream>>>(ids, emb, x);

    dim3 gQKV(QKVLD / 128, MM / 128);    // (24,16)
    dim3 gP(DD / 128, MM / 128);         // (8,16)
    dim3 gUP(UPLD / 128, MM / 128);      // (44,16)
    dim3 gHD(HCHUNK / 128, MM / 128);    // (25,16)
    dim3 gA(SS / 64, HH, BB);
    dim3 gR((MM * 512) / 256, 2);

    for (int li = 0; li < LL; ++li) {
        const float* wq = Wq + (size_t)li * DD * DD;
        const float* wk = Wk + (size_t)li * DD * DD;
        const float* wv = Wv + (size_t)li * DD * DD;
        const float* wo = Wo + (size_t)li * DD * DD;
        const float* w1 = W1 + (size_t)li * FFS * DD;
        const float* w2 = W2 + (size_t)li * DD * FFS;
        const float* w3 = W3 + (size_t)li * FFS * DD;

        k_rmsnorm_bf16<<<MM, 256, 0, stream>>>(x, g1 + (size_t)li * DD, hb);
        k_castw<<<dim3(1, 1024), 256, 0, stream>>>(wq, wqkv,               1024, 256, 256);
        k_castw<<<dim3(1, 1024), 256, 0, stream>>>(wk, wqkv + 1024 * 1024, 1024, 256, 256);
        k_castw<<<dim3(1, 1024), 256, 0, stream>>>(wv, wqkv + 2048 * 1024, 1024, 256, 256);
        k_gemm_bf16<<<gQKV, 256, 0, stream>>>(hb, wqkv, nullptr, qkv, DD, QKVLD);
        k_rope<<<gR, 256, 0, stream>>>(qkv, st, ct);
        k_attn<<<gA, 256, 0, stream>>>(qkv, hb);
        k_castw<<<dim3(1, 1024), 256, 0, stream>>>(wo, wqkv, 1024, 256, 256);
        k_gemm_bf16<<<gP, 256, 0, stream>>>(hb, wqkv, x, x, DD, DD);
        k_rmsnorm_bf16<<<MM, 256, 0, stream>>>(x, g2 + (size_t)li * DD, hb);
        k_castw<<<dim3(1, FFP), 256, 0, stream>>>(w1, w13b,              FFS, 256, 256);
        k_castw<<<dim3(1, FFP), 256, 0, stream>>>(w3, w13b + FFP * 1024, FFS, 256, 256);
        k_gemm_bf16<<<gUP, 256, 0, stream>>>(hb, w13b, nullptr, f13, DD, UPLD);
        k_castw<<<dim3(3, 1024), 256, 0, stream>>>(w2, w2b, 1024, FFS / 4, FFP / 4);
        k_silu_mul<<<dim3(3, MM), 256, 0, stream>>>(f13, f1b);
        k_gemm_bf16<<<gP, 256, 0, stream>>>(f1b, w2b, x, x, FFP, DD);
    }
    k_rmsnorm_bf16<<<MM, 256, 0, stream>>>(x, gf, hb);
    for (int c = 0; c < VV / HCHUNK; ++c) {
        k_castw<<<dim3(1, HCHUNK), 256, 0, stream>>>(Wh + (size_t)c * HCHUNK * DD, whb,
                                                     HCHUNK, 256, 256);
        k_gemm_bf16<<<gHD, 256, 0, stream>>>(hb, whb, nullptr, out + (size_t)c * HCHUNK,
                                             DD, VV);
    }
}